// Round 16
// baseline (154.720 us; speedup 1.0000x reference)
//
#include <hip/hip_runtime.h>
#include <hip/hip_bf16.h>
#include <math.h>

#define N_ 768
#define M_ 768
#define D_ 128
#define H_ 8
#define DH_ 16
#define FF_ 512
#define CH_ 4
#define CM_ 192   // M_/CH_

#define C_LOG2E 1.44269504f
#define C_LN2   0.69314718f

typedef float f32x4 __attribute__((ext_vector_type(4)));
typedef short bf16x8 __attribute__((ext_vector_type(8)));
typedef unsigned short u16x8 __attribute__((ext_vector_type(8)));
typedef unsigned int u32x4 __attribute__((ext_vector_type(4)));

__device__ __forceinline__ float siluf(float x) {
    return x * __builtin_amdgcn_rcpf(1.0f + __expf(-x));
}

__device__ __forceinline__ unsigned short f2bf(float x) {
    unsigned int u = __float_as_uint(x);
    unsigned int r = (u + 0x7fffu + ((u >> 16) & 1u)) >> 16;
    return (unsigned short)r;
}

__device__ __forceinline__ short f2bf_rn(float x) {
    __hip_bfloat16 b = __float2bfloat16(x);
    return (short)*reinterpret_cast<unsigned short*>(&b);
}

__device__ __forceinline__ unsigned int f2bf_pk(float lo, float hi) {
    __hip_bfloat162 h2 = __float22bfloat162_rn(make_float2(lo, hi));
    return *reinterpret_cast<unsigned int*>(&h2);
}

__device__ __forceinline__ float bf2f(unsigned short u) {
    return __uint_as_float(((unsigned int)u) << 16);
}

// ---- prep: We2->bf16 cvt (scaled by -log2e) + We1 transpose ----
__global__ __launch_bounds__(64) void k_prep(const float* __restrict__ We2,
                                             unsigned short* __restrict__ We2b,
                                             const float* __restrict__ We1,
                                             float* __restrict__ We1a) {
    int row = blockIdx.x, lane = threadIdx.x;
    if (row < D_) {
        We2b[row * D_ + lane] = f2bf(We2[row * D_ + lane] * -C_LOG2E);
        We2b[row * D_ + lane + 64] = f2bf(We2[row * D_ + lane + 64] * -C_LOG2E);
    }
    // rows 0..256: We1a[c][j] = We1[j][c]  (row 256 = radial col -> w1r)
    We1a[row * D_ + lane] = We1[lane * 257 + row];
    We1a[row * D_ + lane + 64] = We1[(lane + 64) * 257 + row];
}

// ---- fused LN + projections, 8 rows per block; y-slices: q / k / v / Br ----
__global__ __launch_bounds__(128) void k_qkv4(const float* __restrict__ h_q,
                                              const float* __restrict__ h_r,
                                              const float* __restrict__ g_nq, const float* __restrict__ b_nq,
                                              const float* __restrict__ g_nr, const float* __restrict__ b_nr,
                                              const float* __restrict__ Wq, const float* __restrict__ bq,
                                              const float* __restrict__ Wk, const float* __restrict__ bk,
                                              const float* __restrict__ Wv, const float* __restrict__ bv,
                                              const float* __restrict__ We1a, const float* __restrict__ be1,
                                              float* __restrict__ q,
                                              unsigned short* __restrict__ kb,
                                              unsigned short* __restrict__ vb,
                                              float* __restrict__ Br) {
    int r0 = blockIdx.x * 8, which = blockIdx.y, j = threadIdx.x;
    int wv = j >> 6, ln = j & 63;
    __shared__ float xs[8][D_];
    if (which == 2) {
        for (int i = j; i < 8 * D_; i += 128) xs[i >> 7][i & 127] = h_r[r0 * D_ + i];
    } else {
        const float* src = (which == 0) ? h_q : h_r;
        const float* g = (which == 0) ? g_nq : g_nr;
        const float* b = (which == 0) ? b_nq : b_nr;
        for (int r = wv; r < 8; r += 2) {
            float x0 = src[(r0 + r) * D_ + ln], x1 = src[(r0 + r) * D_ + ln + 64];
            float s = x0 + x1;
#pragma unroll
            for (int o = 32; o > 0; o >>= 1) s += __shfl_xor(s, o);
            float mu = s * (1.f / 128.f);
            float d0 = x0 - mu, d1 = x1 - mu;
            float v2 = d0 * d0 + d1 * d1;
#pragma unroll
            for (int o = 32; o > 0; o >>= 1) v2 += __shfl_xor(v2, o);
            float inv = rsqrtf(v2 * (1.f / 128.f) + 1e-5f);
            xs[r][ln] = d0 * inv * g[ln] + b[ln];
            xs[r][ln + 64] = d1 * inv * g[ln + 64] + b[ln + 64];
        }
    }
    __syncthreads();
    if (which < 3) {
        const float* W = (which == 0) ? Wq : ((which == 1) ? Wk : Wv);
        const float* b = (which == 0) ? bq : ((which == 1) ? bk : bv);
        const float4* Wr = (const float4*)(W + j * D_);
        float acc[8] = {0, 0, 0, 0, 0, 0, 0, 0};
        for (int i = 0; i < 32; i++) {
            float4 w = Wr[i];
#pragma unroll
            for (int r = 0; r < 8; r++) {
                float4 x = ((const float4*)xs[r])[i];
                acc[r] += w.x * x.x + w.y * x.y + w.z * x.z + w.w * x.w;
            }
        }
        float bb = b[j];
        if (which == 0) {
#pragma unroll
            for (int r = 0; r < 8; r++) q[(r0 + r) * D_ + j] = acc[r] + bb;
        } else {
            unsigned short* outb = (which == 1) ? kb : vb;
#pragma unroll
            for (int r = 0; r < 8; r++) outb[(r0 + r) * D_ + j] = (unsigned short)f2bf_rn(acc[r] + bb);
        }
    } else {
        // Br[row][j] = (LN(h_r)[row] . We1[j][128:256] + be1[j]) * -log2e
        float acc[8] = {0, 0, 0, 0, 0, 0, 0, 0};
        for (int i = 0; i < 128; i++) {
            float wv_ = We1a[(128 + i) * D_ + j];
#pragma unroll
            for (int r = 0; r < 8; r++) acc[r] += xs[r][i] * wv_;
        }
        float bb = be1[j];
#pragma unroll
        for (int r = 0; r < 8; r++) Br[(r0 + r) * D_ + j] = (acc[r] + bb) * -C_LOG2E;
    }
}

// ---- attention: one wave per (n, head); bf16 K/V; one barrier ----
__global__ __launch_bounds__(512) void k_attn(const float* __restrict__ q,
                                              const unsigned short* __restrict__ kb,
                                              const unsigned short* __restrict__ vb,
                                              const float* __restrict__ k_null,
                                              const float* __restrict__ v_null,
                                              const float* __restrict__ b_null,
                                              float* __restrict__ a_s,
                                              float* __restrict__ gate,
                                              float* __restrict__ msg) {
    int n = blockIdx.x, t = threadIdx.x;
    int h = t >> 6, lane = t & 63;
    __shared__ float ew[H_][M_];
    __shared__ float gate_p[H_];
    const float inv = 0.25f;

    float qr[DH_];
    const float* qp = q + n * D_ + h * DH_;
#pragma unroll
    for (int d = 0; d < DH_; d++) qr[d] = qp[d];

    float ll[12];
    float lmax = -3.4e38f;
#pragma unroll
    for (int i = 0; i < 12; i++) {
        int m = lane + 64 * i;
        const unsigned short* kp = kb + m * D_ + h * DH_;
        u16x8 k0 = *(const u16x8*)kp;
        u16x8 k1 = *(const u16x8*)(kp + 8);
        float acc = 0.f;
#pragma unroll
        for (int d = 0; d < 8; d++) acc += qr[d] * bf2f(k0[d]);
#pragma unroll
        for (int d = 0; d < 8; d++) acc += qr[d + 8] * bf2f(k1[d]);
        acc *= inv;
        ll[i] = acc;
        lmax = fmaxf(lmax, acc);
    }
#pragma unroll
    for (int o = 32; o > 0; o >>= 1) lmax = fmaxf(lmax, __shfl_xor(lmax, o));
    float es = 0.f;
#pragma unroll
    for (int i = 0; i < 12; i++) es += __expf(ll[i] - lmax);
#pragma unroll
    for (int o = 32; o > 0; o >>= 1) es += __shfl_xor(es, o);

    float lnull;
    {
        const float* kp = k_null + h * DH_;
        float acc = 0.f;
#pragma unroll
        for (int d = 0; d < DH_; d++) acc += qr[d] * kp[d];
        lnull = acc * inv + b_null[h];
    }
    float lse_real = lmax + __logf(es + 1e-9f);
    float m2 = fmaxf(lse_real, lnull);
    float lse_all = m2 + __logf(__expf(lse_real - m2) + __expf(lnull - m2));
    float a_null = __expf(lnull - lse_all);
    if (lane == 0) gate_p[h] = fminf(1.f, __expf(lse_real - lse_all));

#pragma unroll
    for (int i = 0; i < 12; i++) ew[h][lane + 64 * i] = __expf(ll[i] - lse_all);

    int d = lane & 15, sub = lane >> 4;
    float p = 0.f;
    const f32x4* ewv = (const f32x4*)&ew[h][0];
#pragma unroll 4
    for (int i = 0; i < 48; i++) {
        int m0 = i * 16 + sub * 4;
        f32x4 a4 = ewv[i * 4 + sub];
        const unsigned short* vp = vb + m0 * D_ + h * DH_ + d;
        p += a4[0] * bf2f(vp[0]);
        p += a4[1] * bf2f(vp[D_]);
        p += a4[2] * bf2f(vp[2 * D_]);
        p += a4[3] * bf2f(vp[3 * D_]);
    }
    p += __shfl_xor(p, 16);
    p += __shfl_xor(p, 32);
    if (lane < 16) msg[n * D_ + h * DH_ + lane] = p + a_null * v_null[h * DH_ + lane];

    __syncthreads();
    for (int m = t; m < M_; m += 512) {
        float s = 0.f;
#pragma unroll
        for (int hh = 0; hh < H_; hh++) s += ew[hh][m];
        a_s[n * M_ + m] = s * 0.125f;
    }
    if (t == 0) {
        float s = 0.f;
#pragma unroll
        for (int hh = 0; hh < H_; hh++) s += gate_p[hh];
        gate[n] = s * 0.125f;
    }
}

// ---- fused outproj + LN + ffn1 + ffn2 + LN, 4 rows per block (192 blocks) ----
__global__ __launch_bounds__(256) void k_mlp(const float* __restrict__ h_q,
                                             const float* __restrict__ msg,
                                             const float* __restrict__ Wo, const float* __restrict__ bop,
                                             const float* __restrict__ g_ff, const float* __restrict__ b_ff,
                                             const float* __restrict__ W1, const float* __restrict__ b1,
                                             const float* __restrict__ W2, const float* __restrict__ b2,
                                             const float* __restrict__ g_nq, const float* __restrict__ b_nq,
                                             float* __restrict__ h_out, float* __restrict__ qh_new) {
    int r0 = blockIdx.x * 4;
    int t = threadIdx.x;
    __shared__ float xs[4][D_];
    __shared__ float hm[4][D_];
    __shared__ float tl[4][D_];
    __shared__ float ffh[4][FF_];
    for (int i = t; i < 4 * D_; i += 256) xs[i >> 7][i & 127] = msg[r0 * D_ + i];
    __syncthreads();
    {
        int g = t >> 7, j = t & 127;
        float acc[2] = {0, 0};
        const float4* Wr = (const float4*)(Wo + j * D_);
        for (int i = 0; i < 32; i++) {
            float4 w = Wr[i];
#pragma unroll
            for (int r = 0; r < 2; r++) {
                float4 x = ((const float4*)xs[2 * g + r])[i];
                acc[r] += w.x * x.x + w.y * x.y + w.z * x.z + w.w * x.w;
            }
        }
        float bb = bop[j];
#pragma unroll
        for (int r = 0; r < 2; r++)
            hm[2 * g + r][j] = h_q[(r0 + 2 * g + r) * D_ + j] + acc[r] + bb;
    }
    __syncthreads();
    {
        int r = t >> 6, l = t & 63;
        float v0 = hm[r][l], v1 = hm[r][l + 64];
        float s = v0 + v1;
#pragma unroll
        for (int o = 32; o > 0; o >>= 1) s += __shfl_xor(s, o);
        float mu = s * (1.f / 128.f);
        float d0 = v0 - mu, d1 = v1 - mu;
        float vv = d0 * d0 + d1 * d1;
#pragma unroll
        for (int o = 32; o > 0; o >>= 1) vv += __shfl_xor(vv, o);
        float inv = rsqrtf(vv * (1.f / 128.f) + 1e-5f);
        tl[r][l] = d0 * inv * g_ff[l] + b_ff[l];
        tl[r][l + 64] = d1 * inv * g_ff[l + 64] + b_ff[l + 64];
    }
    __syncthreads();
    {
        int j0 = t, j1 = t + 256;
        float a0[4] = {0}, a1[4] = {0};
        const float4* Wa = (const float4*)(W1 + j0 * D_);
        const float4* Wb = (const float4*)(W1 + j1 * D_);
        for (int i = 0; i < 32; i++) {
            float4 wa = Wa[i], wb = Wb[i];
#pragma unroll
            for (int r = 0; r < 4; r++) {
                float4 x = ((const float4*)tl[r])[i];
                a0[r] += wa.x * x.x + wa.y * x.y + wa.z * x.z + wa.w * x.w;
                a1[r] += wb.x * x.x + wb.y * x.y + wb.z * x.z + wb.w * x.w;
            }
        }
        float bb0 = b1[j0], bb1 = b1[j1];
#pragma unroll
        for (int r = 0; r < 4; r++) {
            ffh[r][j0] = siluf(a0[r] + bb0);
            ffh[r][j1] = siluf(a1[r] + bb1);
        }
    }
    __syncthreads();
    {
        int g = t >> 7, j = t & 127;
        float acc[2] = {0, 0};
        const float4* Wr = (const float4*)(W2 + j * FF_);
        for (int i = 0; i < 128; i++) {
            float4 w = Wr[i];
#pragma unroll
            for (int r = 0; r < 2; r++) {
                float4 x = ((const float4*)ffh[2 * g + r])[i];
                acc[r] += w.x * x.x + w.y * x.y + w.z * x.z + w.w * x.w;
            }
        }
        float bb = b2[j];
#pragma unroll
        for (int r = 0; r < 2; r++) {
            float vv = hm[2 * g + r][j] + acc[r] + bb;
            h_out[(r0 + 2 * g + r) * D_ + j] = vv;
            hm[2 * g + r][j] = vv;
        }
    }
    __syncthreads();
    {
        int r = t >> 6, l = t & 63;
        float v0 = hm[r][l], v1 = hm[r][l + 64];
        float s = v0 + v1;
#pragma unroll
        for (int o = 32; o > 0; o >>= 1) s += __shfl_xor(s, o);
        float mu = s * (1.f / 128.f);
        float d0 = v0 - mu, d1 = v1 - mu;
        float vv = d0 * d0 + d1 * d1;
#pragma unroll
        for (int o = 32; o > 0; o >>= 1) vv += __shfl_xor(vv, o);
        float inv = rsqrtf(vv * (1.f / 128.f) + 1e-5f);
        int rr = (r0 + r) * D_;
        qh_new[rr + l] = d0 * inv * g_nq[l] + b_nq[l];
        qh_new[rr + l + 64] = d1 * inv * g_nq[l + 64] + b_nq[l + 64];
    }
}

// ---- Aq precompute only (96 blocks), output pre-scaled by -log2e ----
__global__ __launch_bounds__(256) void k_preA(const float* __restrict__ qh_new,
                                              const float* __restrict__ We1a,
                                              float* __restrict__ Aq) {
    int r0 = blockIdx.x * 8;
    int t = threadIdx.x;
    int r = t >> 5, jg = t & 31;
    __shared__ float xs[8][D_];
    for (int i = t; i < 8 * D_; i += 256) xs[i >> 7][i & 127] = qh_new[r0 * D_ + i];
    __syncthreads();
    float acc[4] = {0, 0, 0, 0};
    const float* xr = xs[r];
    for (int i = 0; i < 128; i++) {
        float x = xr[i];
        const float4 w0 = *(const float4*)(We1a + i * D_ + jg * 4);
        acc[0] += w0.x * x; acc[1] += w0.y * x; acc[2] += w0.z * x; acc[3] += w0.w * x;
    }
    float* out = Aq + (r0 + r) * D_ + jg * 4;
    *(float4*)(out) = make_float4(acc[0] * -C_LOG2E, acc[1] * -C_LOG2E,
                                  acc[2] * -C_LOG2E, acc[3] * -C_LOG2E);
}

// ---- pair kernel (round-14 champion): B in LDS, af in regs, no in-loop
// barriers, full m-unroll, pt-unroll 2, exp2 folding, loads in-loop ----
__global__ __launch_bounds__(256, 3) void k_pair(const float* __restrict__ x_q,
                                                 const float* __restrict__ x_r,
                                                 const float* __restrict__ Aq,
                                                 const float* __restrict__ Br,
                                                 const float* __restrict__ w1r,
                                                 const float* __restrict__ be2,
                                                 const float* __restrict__ Ws,
                                                 const unsigned short* __restrict__ We2b,
                                                 const float* __restrict__ a_s,
                                                 float* __restrict__ dxp) {
    int n = blockIdx.x;
    int chunk = blockIdx.y;
    int cm = chunk * CM_;
    int t = threadIdx.x;
    int w = t >> 6;
    int lane = t & 63;
    int col = lane & 15;
    int kg = lane >> 4;

    __shared__ bf16x8 b_lds[8][4][64];   // 32 KB: We2 fragments (c-scaled)
    __shared__ float xr_l[CM_ * 3];
    __shared__ float as_l[CM_];
    __shared__ float Aq_l[D_];           // c-scaled (from k_preA)
    __shared__ float w1r_l[D_];          // c-scaled here
    __shared__ float2 bw_l[D_];          // (c*be2, -ln2*Ws)
    __shared__ float dxw[4][3];

#pragma unroll
    for (int pp = 0; pp < 2; pp++) {
        int pt = w * 2 + pp;
#pragma unroll
        for (int kt = 0; kt < 4; kt++)
            b_lds[pt][kt][lane] = *reinterpret_cast<const bf16x8*>(We2b + (pt * 16 + col) * D_ + kt * 32 + kg * 8);
    }
    for (int i = t; i < CM_ * 3; i += 256) xr_l[i] = x_r[cm * 3 + i];
    if (t < CM_) as_l[t] = a_s[n * M_ + cm + t];
    if (t < D_) {
        Aq_l[t] = Aq[n * D_ + t];
        w1r_l[t] = w1r[t] * -C_LOG2E;
        bw_l[t] = make_float2(be2[t] * -C_LOG2E, Ws[t] * -C_LN2);
    }
    __syncthreads();   // the only block-wide barrier before the epilogue

    float xq0 = x_q[n * 3 + 0], xq1 = x_q[n * 3 + 1], xq2 = x_q[n * 3 + 2];
    float dxa = 0.f, dya = 0.f, dza = 0.f;

#pragma unroll
    for (int it = 0; it < CM_ / 64; it++) {
        int pm = it * 64 + w * 16 + col;
        float d0 = xq0 - xr_l[pm * 3], d1 = xq1 - xr_l[pm * 3 + 1], d2 = xq2 - xr_l[pm * 3 + 2];
        float radial = d0 * d0 + d1 * d1 + d2 * d2;
        float ir = rsqrtf(radial + 1e-8f);
        // build af (h1 fragments) in registers; y = -log2e * h1arg
        bf16x8 af[4];
#pragma unroll
        for (int kt = 0; kt < 4; kt++) {
            int ob = kt * 32 + kg * 8;
            const float4* brp = reinterpret_cast<const float4*>(Br + (cm + pm) * D_ + ob);
            float4 b0 = brp[0], b1 = brp[1];
            const float4 a0 = *(const float4*)(Aq_l + ob), a1 = *(const float4*)(Aq_l + ob + 4);
            const float4 w0 = *(const float4*)(w1r_l + ob), w1 = *(const float4*)(w1r_l + ob + 4);
            float y0 = a0.x + b0.x + radial * w0.x;
            float y1 = a0.y + b0.y + radial * w0.y;
            float y2 = a0.z + b0.z + radial * w0.z;
            float y3 = a0.w + b0.w + radial * w0.w;
            float y4 = a1.x + b1.x + radial * w1.x;
            float y5 = a1.y + b1.y + radial * w1.y;
            float y6 = a1.z + b1.z + radial * w1.z;
            float y7 = a1.w + b1.w + radial * w1.w;
            float s0 = (y0 * -C_LN2) * __builtin_amdgcn_rcpf(1.f + __builtin_amdgcn_exp2f(y0));
            float s1 = (y1 * -C_LN2) * __builtin_amdgcn_rcpf(1.f + __builtin_amdgcn_exp2f(y1));
            float s2 = (y2 * -C_LN2) * __builtin_amdgcn_rcpf(1.f + __builtin_amdgcn_exp2f(y2));
            float s3 = (y3 * -C_LN2) * __builtin_amdgcn_rcpf(1.f + __builtin_amdgcn_exp2f(y3));
            float s4 = (y4 * -C_LN2) * __builtin_amdgcn_rcpf(1.f + __builtin_amdgcn_exp2f(y4));
            float s5 = (y5 * -C_LN2) * __builtin_amdgcn_rcpf(1.f + __builtin_amdgcn_exp2f(y5));
            float s6 = (y6 * -C_LN2) * __builtin_amdgcn_rcpf(1.f + __builtin_amdgcn_exp2f(y6));
            float s7 = (y7 * -C_LN2) * __builtin_amdgcn_rcpf(1.f + __builtin_amdgcn_exp2f(y7));
            u32x4 afp;
            afp[0] = f2bf_pk(s0, s1);
            afp[1] = f2bf_pk(s2, s3);
            afp[2] = f2bf_pk(s4, s5);
            afp[3] = f2bf_pk(s6, s7);
            af[kt] = *reinterpret_cast<bf16x8*>(&afp);
        }
        // p-sweep: acc = c*(We2 . silu_h); layer-2 silu via exp2, Ws fold
        float svt = 0.f;
#pragma unroll 2
        for (int pt = 0; pt < 8; pt++) {
            f32x4 acc = {0.f, 0.f, 0.f, 0.f};
#pragma unroll
            for (int kt = 0; kt < 4; kt++)
                acc = __builtin_amdgcn_mfma_f32_16x16x32_bf16(b_lds[pt][kt][lane], af[kt], acc, 0, 0, 0);
#pragma unroll
            for (int r = 0; r < 4; r++) {
                float2 bw = bw_l[pt * 16 + kg * 4 + r];
                float y = acc[r] + bw.x;     // = -log2e * (z)
                float rc = __builtin_amdgcn_rcpf(1.f + __builtin_amdgcn_exp2f(y));
                svt = fmaf(y * rc, bw.y, svt);   // y*rc*(-ln2*Ws) = silu(z)*Ws
            }
        }
        float sw = svt * as_l[pm];
        dxa += d0 * ir * sw;
        dya += d1 * ir * sw;
        dza += d2 * ir * sw;
    }
    // wave-level reduce, then tiny cross-wave combine
#pragma unroll
    for (int o = 1; o < 64; o <<= 1) {
        dxa += __shfl_xor(dxa, o);
        dya += __shfl_xor(dya, o);
        dza += __shfl_xor(dza, o);
    }
    if (lane == 0) { dxw[w][0] = dxa; dxw[w][1] = dya; dxw[w][2] = dza; }
    __syncthreads();
    if (t == 0) {
        float* o = dxp + (chunk * N_ + n) * 3;
        o[0] = dxw[0][0] + dxw[1][0] + dxw[2][0] + dxw[3][0];
        o[1] = dxw[0][1] + dxw[1][1] + dxw[2][1] + dxw[3][1];
        o[2] = dxw[0][2] + dxw[1][2] + dxw[2][2] + dxw[3][2];
    }
}

// ---- finalize ----
__global__ __launch_bounds__(256) void k_fin(const float* __restrict__ x_q,
                                             const float* __restrict__ dxp,
                                             const float* __restrict__ gate,
                                             float* __restrict__ x_out) {
    int i = blockIdx.x * 256 + threadIdx.x;
    if (i >= N_ * 3) return;
    int n = i / 3;
    float s = 0.f;
#pragma unroll
    for (int ch = 0; ch < CH_; ch++) s += dxp[(ch * N_ + n) * 3 + (i - n * 3)];
    x_out[i] = x_q[i] + s * gate[n];
}

extern "C" void kernel_launch(void* const* d_in, const int* in_sizes, int n_in,
                              void* d_out, int out_size, void* d_ws, size_t ws_size,
                              hipStream_t stream) {
    const float* h_q   = (const float*)d_in[0];
    const float* x_q   = (const float*)d_in[1];
    const float* h_r   = (const float*)d_in[2];
    const float* x_r   = (const float*)d_in[3];
    const float* Wq    = (const float*)d_in[6];
    const float* bqp   = (const float*)d_in[7];
    const float* Wk    = (const float*)d_in[8];
    const float* bkp   = (const float*)d_in[9];
    const float* Wv    = (const float*)d_in[10];
    const float* bvp   = (const float*)d_in[11];
    const float* Wo    = (const float*)d_in[12];
    const float* bop   = (const float*)d_in[13];
    const float* g_nq  = (const float*)d_in[14];
    const float* b_nq  = (const float*)d_in[15];
    const float* g_nr  = (const float*)d_in[16];
    const float* b_nr  = (const float*)d_in[17];
    const float* g_ff  = (const float*)d_in[18];
    const float* b_ff  = (const float*)d_in[19];
    const float* W1    = (const float*)d_in[20];
    const float* b1    = (const float*)d_in[21];
    const float* W2    = (const float*)d_in[22];
    const float* b2    = (const float*)d_in[23];
    const float* k_null= (const float*)d_in[24];
    const float* v_null= (const float*)d_in[25];
    const float* b_null= (const float*)d_in[26];
    const float* We1   = (const float*)d_in[27];
    const float* be1   = (const float*)d_in[28];
    const float* We2   = (const float*)d_in[29];
    const float* be2   = (const float*)d_in[30];
    const float* Ws    = (const float*)d_in[31];

    float* ws     = (float*)d_ws;
    float* q      = ws;                   // N*D
    unsigned short* kb = (unsigned short*)(q + N_ * D_);  // M*D bf16
    unsigned short* vb = kb + M_ * D_;                    // M*D bf16
    float* a_s    = (float*)(vb + M_ * D_);  // N*M
    float* gate   = a_s + N_ * M_;        // N
    float* msg    = gate + N_;            // N*D
    float* qh_new = msg + N_ * D_;        // N*D
    float* Aq     = qh_new + N_ * D_;     // N*D
    float* Br     = Aq + N_ * D_;         // M*D
    float* We1a   = Br + M_ * D_;         // 257*128 (row 256 = w1r)
    float* dxp    = We1a + 257 * D_;      // CH*N*3
    unsigned short* We2b = (unsigned short*)(dxp + CH_ * N_ * 3);  // D*D bf16
    float* w1r    = We1a + 256 * D_;

    float* h_out = (float*)d_out;         // N*D
    float* x_out = h_out + N_ * D_;       // N*3

    k_prep<<<257, 64, 0, stream>>>(We2, We2b, We1, We1a);
    k_qkv4<<<dim3(96, 4), 128, 0, stream>>>(h_q, h_r, g_nq, b_nq, g_nr, b_nr,
                                            Wq, bqp, Wk, bkp, Wv, bvp, We1a, be1,
                                            q, kb, vb, Br);
    k_attn<<<N_, 512, 0, stream>>>(q, kb, vb, k_null, v_null, b_null, a_s, gate, msg);
    k_mlp<<<192, 256, 0, stream>>>(h_q, msg, Wo, bop, g_ff, b_ff, W1, b1, W2, b2, g_nq, b_nq, h_out, qh_new);
    k_preA<<<96, 256, 0, stream>>>(qh_new, We1a, Aq);
    k_pair<<<dim3(N_, CH_), 256, 0, stream>>>(x_q, x_r, Aq, Br, w1r, be2, Ws, We2b, a_s, dxp);
    k_fin<<<9, 256, 0, stream>>>(x_q, dxp, gate, x_out);
}

// Round 17
// 147.273 us; speedup vs baseline: 1.0506x; 1.0506x over previous
//
#include <hip/hip_runtime.h>
#include <hip/hip_bf16.h>
#include <math.h>

#define N_ 768
#define M_ 768
#define D_ 128
#define H_ 8
#define DH_ 16
#define FF_ 512
#define CH_ 3
#define CM_ 256   // M_/CH_

#define C_LOG2E 1.44269504f
#define C_LN2   0.69314718f

typedef float f32x4 __attribute__((ext_vector_type(4)));
typedef short bf16x8 __attribute__((ext_vector_type(8)));
typedef unsigned short u16x8 __attribute__((ext_vector_type(8)));
typedef unsigned int u32x4 __attribute__((ext_vector_type(4)));

__device__ __forceinline__ float siluf(float x) {
    return x * __builtin_amdgcn_rcpf(1.0f + __expf(-x));
}

__device__ __forceinline__ unsigned short f2bf(float x) {
    unsigned int u = __float_as_uint(x);
    unsigned int r = (u + 0x7fffu + ((u >> 16) & 1u)) >> 16;
    return (unsigned short)r;
}

__device__ __forceinline__ short f2bf_rn(float x) {
    __hip_bfloat16 b = __float2bfloat16(x);
    return (short)*reinterpret_cast<unsigned short*>(&b);
}

__device__ __forceinline__ unsigned int f2bf_pk(float lo, float hi) {
    __hip_bfloat162 h2 = __float22bfloat162_rn(make_float2(lo, hi));
    return *reinterpret_cast<unsigned int*>(&h2);
}

__device__ __forceinline__ float bf2f(unsigned short u) {
    return __uint_as_float(((unsigned int)u) << 16);
}

// ---- LN for qh & rh rows + We2->bf16 cvt (scaled by -log2e) + We1 transpose ----
__global__ __launch_bounds__(64) void k_ln2(const float* __restrict__ h_q,
                                            const float* __restrict__ h_r,
                                            const float* __restrict__ g_nq, const float* __restrict__ b_nq,
                                            const float* __restrict__ g_nr, const float* __restrict__ b_nr,
                                            float* __restrict__ qh, float* __restrict__ rh,
                                            const float* __restrict__ We2, unsigned short* __restrict__ We2b,
                                            const float* __restrict__ We1, float* __restrict__ We1a) {
    int row = blockIdx.x, lane = threadIdx.x;
    const float *src, *g, *b; float* dst;
    if (row < N_) { src = h_q + row * D_; g = g_nq; b = b_nq; dst = qh + row * D_; }
    else { src = h_r + (row - N_) * D_; g = g_nr; b = b_nr; dst = rh + (row - N_) * D_; }
    float x0 = src[lane], x1 = src[lane + 64];
    float s = x0 + x1;
#pragma unroll
    for (int o = 32; o > 0; o >>= 1) s += __shfl_xor(s, o);
    float mu = s * (1.f / 128.f);
    float d0 = x0 - mu, d1 = x1 - mu;
    float v2 = d0 * d0 + d1 * d1;
#pragma unroll
    for (int o = 32; o > 0; o >>= 1) v2 += __shfl_xor(v2, o);
    float inv = rsqrtf(v2 * (1.f / 128.f) + 1e-5f);
    dst[lane] = d0 * inv * g[lane] + b[lane];
    dst[lane + 64] = d1 * inv * g[lane + 64] + b[lane + 64];
    if (row < D_) {
        We2b[row * D_ + lane] = f2bf(We2[row * D_ + lane] * -C_LOG2E);
        We2b[row * D_ + lane + 64] = f2bf(We2[row * D_ + lane + 64] * -C_LOG2E);
    }
    if (row <= 256) {
        We1a[row * D_ + lane] = We1[lane * 257 + row];
        We1a[row * D_ + lane + 64] = We1[(lane + 64) * 257 + row];
    }
}

// ---- q/k/v projections, 8 rows per block; k,v emitted as bf16 ----
__global__ __launch_bounds__(128) void k_qkv(const float* __restrict__ qh,
                                             const float* __restrict__ rh,
                                             const float* __restrict__ h_r,
                                             const float* __restrict__ Wq, const float* __restrict__ bq,
                                             const float* __restrict__ Wk, const float* __restrict__ bk,
                                             const float* __restrict__ Wv, const float* __restrict__ bv,
                                             float* __restrict__ q,
                                             unsigned short* __restrict__ kb,
                                             unsigned short* __restrict__ vb) {
    int r0 = blockIdx.x * 8, which = blockIdx.y, j = threadIdx.x;
    const float* in; const float* W; const float* b;
    if (which == 0) { in = qh; W = Wq; b = bq; }
    else if (which == 1) { in = rh; W = Wk; b = bk; }
    else { in = h_r; W = Wv; b = bv; }
    __shared__ float xs[8][D_];
    for (int i = j; i < 8 * D_; i += 128) xs[i >> 7][i & 127] = in[r0 * D_ + i];
    __syncthreads();
    const float4* Wr = (const float4*)(W + j * D_);
    float acc[8] = {0, 0, 0, 0, 0, 0, 0, 0};
    for (int i = 0; i < 32; i++) {
        float4 w = Wr[i];
#pragma unroll
        for (int r = 0; r < 8; r++) {
            float4 x = ((const float4*)xs[r])[i];
            acc[r] += w.x * x.x + w.y * x.y + w.z * x.z + w.w * x.w;
        }
    }
    float bb = b[j];
    if (which == 0) {
#pragma unroll
        for (int r = 0; r < 8; r++) q[(r0 + r) * D_ + j] = acc[r] + bb;
    } else {
        unsigned short* outb = (which == 1) ? kb : vb;
#pragma unroll
        for (int r = 0; r < 8; r++) outb[(r0 + r) * D_ + j] = (unsigned short)f2bf_rn(acc[r] + bb);
    }
}

// ---- attention: one wave per (n, head); bf16 K/V; one barrier ----
__global__ __launch_bounds__(512) void k_attn(const float* __restrict__ q,
                                              const unsigned short* __restrict__ kb,
                                              const unsigned short* __restrict__ vb,
                                              const float* __restrict__ k_null,
                                              const float* __restrict__ v_null,
                                              const float* __restrict__ b_null,
                                              float* __restrict__ a_s,
                                              float* __restrict__ gate,
                                              float* __restrict__ msg) {
    int n = blockIdx.x, t = threadIdx.x;
    int h = t >> 6, lane = t & 63;
    __shared__ float ew[H_][M_];
    __shared__ float gate_p[H_];
    const float inv = 0.25f;

    float qr[DH_];
    const float* qp = q + n * D_ + h * DH_;
#pragma unroll
    for (int d = 0; d < DH_; d++) qr[d] = qp[d];

    float ll[12];
    float lmax = -3.4e38f;
#pragma unroll
    for (int i = 0; i < 12; i++) {
        int m = lane + 64 * i;
        const unsigned short* kp = kb + m * D_ + h * DH_;
        u16x8 k0 = *(const u16x8*)kp;
        u16x8 k1 = *(const u16x8*)(kp + 8);
        float acc = 0.f;
#pragma unroll
        for (int d = 0; d < 8; d++) acc += qr[d] * bf2f(k0[d]);
#pragma unroll
        for (int d = 0; d < 8; d++) acc += qr[d + 8] * bf2f(k1[d]);
        acc *= inv;
        ll[i] = acc;
        lmax = fmaxf(lmax, acc);
    }
#pragma unroll
    for (int o = 32; o > 0; o >>= 1) lmax = fmaxf(lmax, __shfl_xor(lmax, o));
    float es = 0.f;
#pragma unroll
    for (int i = 0; i < 12; i++) es += __expf(ll[i] - lmax);
#pragma unroll
    for (int o = 32; o > 0; o >>= 1) es += __shfl_xor(es, o);

    float lnull;
    {
        const float* kp = k_null + h * DH_;
        float acc = 0.f;
#pragma unroll
        for (int d = 0; d < DH_; d++) acc += qr[d] * kp[d];
        lnull = acc * inv + b_null[h];
    }
    float lse_real = lmax + __logf(es + 1e-9f);
    float m2 = fmaxf(lse_real, lnull);
    float lse_all = m2 + __logf(__expf(lse_real - m2) + __expf(lnull - m2));
    float a_null = __expf(lnull - lse_all);
    if (lane == 0) gate_p[h] = fminf(1.f, __expf(lse_real - lse_all));

#pragma unroll
    for (int i = 0; i < 12; i++) ew[h][lane + 64 * i] = __expf(ll[i] - lse_all);

    int d = lane & 15, sub = lane >> 4;
    float p = 0.f;
    const f32x4* ewv = (const f32x4*)&ew[h][0];
#pragma unroll 4
    for (int i = 0; i < 48; i++) {
        int m0 = i * 16 + sub * 4;
        f32x4 a4 = ewv[i * 4 + sub];
        const unsigned short* vp = vb + m0 * D_ + h * DH_ + d;
        p += a4[0] * bf2f(vp[0]);
        p += a4[1] * bf2f(vp[D_]);
        p += a4[2] * bf2f(vp[2 * D_]);
        p += a4[3] * bf2f(vp[3 * D_]);
    }
    p += __shfl_xor(p, 16);
    p += __shfl_xor(p, 32);
    if (lane < 16) msg[n * D_ + h * DH_ + lane] = p + a_null * v_null[h * DH_ + lane];

    __syncthreads();
    for (int m = t; m < M_; m += 512) {
        float s = 0.f;
#pragma unroll
        for (int hh = 0; hh < H_; hh++) s += ew[hh][m];
        a_s[n * M_ + m] = s * 0.125f;
    }
    if (t == 0) {
        float s = 0.f;
#pragma unroll
        for (int hh = 0; hh < H_; hh++) s += gate_p[hh];
        gate[n] = s * 0.125f;
    }
}

// ---- fused outproj + LN + ffn1 + ffn2 + LN, 4 rows per block (192 blocks) ----
__global__ __launch_bounds__(256) void k_mlp(const float* __restrict__ h_q,
                                             const float* __restrict__ msg,
                                             const float* __restrict__ Wo, const float* __restrict__ bop,
                                             const float* __restrict__ g_ff, const float* __restrict__ b_ff,
                                             const float* __restrict__ W1, const float* __restrict__ b1,
                                             const float* __restrict__ W2, const float* __restrict__ b2,
                                             const float* __restrict__ g_nq, const float* __restrict__ b_nq,
                                             float* __restrict__ h_out, float* __restrict__ qh_new) {
    int r0 = blockIdx.x * 4;
    int t = threadIdx.x;
    __shared__ float xs[4][D_];
    __shared__ float hm[4][D_];
    __shared__ float tl[4][D_];
    __shared__ float ffh[4][FF_];
    for (int i = t; i < 4 * D_; i += 256) xs[i >> 7][i & 127] = msg[r0 * D_ + i];
    __syncthreads();
    {
        int g = t >> 7, j = t & 127;
        float acc[2] = {0, 0};
        const float4* Wr = (const float4*)(Wo + j * D_);
        for (int i = 0; i < 32; i++) {
            float4 w = Wr[i];
#pragma unroll
            for (int r = 0; r < 2; r++) {
                float4 x = ((const float4*)xs[2 * g + r])[i];
                acc[r] += w.x * x.x + w.y * x.y + w.z * x.z + w.w * x.w;
            }
        }
        float bb = bop[j];
#pragma unroll
        for (int r = 0; r < 2; r++)
            hm[2 * g + r][j] = h_q[(r0 + 2 * g + r) * D_ + j] + acc[r] + bb;
    }
    __syncthreads();
    {
        int r = t >> 6, l = t & 63;
        float v0 = hm[r][l], v1 = hm[r][l + 64];
        float s = v0 + v1;
#pragma unroll
        for (int o = 32; o > 0; o >>= 1) s += __shfl_xor(s, o);
        float mu = s * (1.f / 128.f);
        float d0 = v0 - mu, d1 = v1 - mu;
        float vv = d0 * d0 + d1 * d1;
#pragma unroll
        for (int o = 32; o > 0; o >>= 1) vv += __shfl_xor(vv, o);
        float inv = rsqrtf(vv * (1.f / 128.f) + 1e-5f);
        tl[r][l] = d0 * inv * g_ff[l] + b_ff[l];
        tl[r][l + 64] = d1 * inv * g_ff[l + 64] + b_ff[l + 64];
    }
    __syncthreads();
    {
        int j0 = t, j1 = t + 256;
        float a0[4] = {0}, a1[4] = {0};
        const float4* Wa = (const float4*)(W1 + j0 * D_);
        const float4* Wb = (const float4*)(W1 + j1 * D_);
        for (int i = 0; i < 32; i++) {
            float4 wa = Wa[i], wb = Wb[i];
#pragma unroll
            for (int r = 0; r < 4; r++) {
                float4 x = ((const float4*)tl[r])[i];
                a0[r] += wa.x * x.x + wa.y * x.y + wa.z * x.z + wa.w * x.w;
                a1[r] += wb.x * x.x + wb.y * x.y + wb.z * x.z + wb.w * x.w;
            }
        }
        float bb0 = b1[j0], bb1 = b1[j1];
#pragma unroll
        for (int r = 0; r < 4; r++) {
            ffh[r][j0] = siluf(a0[r] + bb0);
            ffh[r][j1] = siluf(a1[r] + bb1);
        }
    }
    __syncthreads();
    {
        int g = t >> 7, j = t & 127;
        float acc[2] = {0, 0};
        const float4* Wr = (const float4*)(W2 + j * FF_);
        for (int i = 0; i < 128; i++) {
            float4 w = Wr[i];
#pragma unroll
            for (int r = 0; r < 2; r++) {
                float4 x = ((const float4*)ffh[2 * g + r])[i];
                acc[r] += w.x * x.x + w.y * x.y + w.z * x.z + w.w * x.w;
            }
        }
        float bb = b2[j];
#pragma unroll
        for (int r = 0; r < 2; r++) {
            float vv = hm[2 * g + r][j] + acc[r] + bb;
            h_out[(r0 + 2 * g + r) * D_ + j] = vv;
            hm[2 * g + r][j] = vv;
        }
    }
    __syncthreads();
    {
        int r = t >> 6, l = t & 63;
        float v0 = hm[r][l], v1 = hm[r][l + 64];
        float s = v0 + v1;
#pragma unroll
        for (int o = 32; o > 0; o >>= 1) s += __shfl_xor(s, o);
        float mu = s * (1.f / 128.f);
        float d0 = v0 - mu, d1 = v1 - mu;
        float vv = d0 * d0 + d1 * d1;
#pragma unroll
        for (int o = 32; o > 0; o >>= 1) vv += __shfl_xor(vv, o);
        float inv = rsqrtf(vv * (1.f / 128.f) + 1e-5f);
        int rr = (r0 + r) * D_;
        qh_new[rr + l] = d0 * inv * g_nq[l] + b_nq[l];
        qh_new[rr + l + 64] = d1 * inv * g_nq[l + 64] + b_nq[l + 64];
    }
}

// ---- edge-MLP layer-1 precompute (outputs pre-scaled by -log2e) ----
__global__ __launch_bounds__(256) void k_pre(const float* __restrict__ qh_new,
                                             const float* __restrict__ rh,
                                             const float* __restrict__ We1a,
                                             const float* __restrict__ be1,
                                             float* __restrict__ Aq,
                                             float* __restrict__ Br) {
    int bb = blockIdx.x;               // 0..191
    int half = bb >= 96;
    int r0 = (bb - half * 96) * 8;
    int off = half * 128;
    int t = threadIdx.x;
    int r = t >> 5, jg = t & 31;       // row 0..7, j-group of 4
    __shared__ float xs[8][D_];
    const float* in = (half ? rh : qh_new) + r0 * D_;
    for (int i = t; i < 8 * D_; i += 256) xs[i >> 7][i & 127] = in[i];
    __syncthreads();
    float acc[4] = {0, 0, 0, 0};
    const float* xr = xs[r];
    for (int i = 0; i < 128; i++) {
        float x = xr[i];
        const float4 w0 = *(const float4*)(We1a + (off + i) * D_ + jg * 4);
        acc[0] += w0.x * x; acc[1] += w0.y * x; acc[2] += w0.z * x; acc[3] += w0.w * x;
    }
    if (half) {
        const float4 e0 = *(const float4*)(be1 + jg * 4);
        acc[0] += e0.x; acc[1] += e0.y; acc[2] += e0.z; acc[3] += e0.w;
    }
    float* out = (half ? Br : Aq) + (r0 + r) * D_ + jg * 4;
    *(float4*)(out) = make_float4(acc[0] * -C_LOG2E, acc[1] * -C_LOG2E,
                                  acc[2] * -C_LOG2E, acc[3] * -C_LOG2E);
}

// ---- pair kernel (r14 champion, CH=3): B in LDS, af in regs, no in-loop
// barriers, full m-unroll (4 iters), pt-unroll 2, exp2 folding ----
__global__ __launch_bounds__(256, 3) void k_pair(const float* __restrict__ x_q,
                                                 const float* __restrict__ x_r,
                                                 const float* __restrict__ Aq,
                                                 const float* __restrict__ Br,
                                                 const float* __restrict__ w1r,
                                                 const float* __restrict__ be2,
                                                 const float* __restrict__ Ws,
                                                 const unsigned short* __restrict__ We2b,
                                                 const float* __restrict__ a_s,
                                                 float* __restrict__ dxp) {
    int n = blockIdx.x;
    int chunk = blockIdx.y;
    int cm = chunk * CM_;
    int t = threadIdx.x;
    int w = t >> 6;
    int lane = t & 63;
    int col = lane & 15;
    int kg = lane >> 4;

    __shared__ bf16x8 b_lds[8][4][64];   // 32 KB: We2 fragments (c-scaled)
    __shared__ float xr_l[CM_ * 3];      // 3 KB
    __shared__ float as_l[CM_];          // 1 KB
    __shared__ float Aq_l[D_];           // c-scaled (from k_pre)
    __shared__ float w1r_l[D_];          // c-scaled here
    __shared__ float2 bw_l[D_];          // (c*be2, -ln2*Ws)
    __shared__ float dxw[4][3];

#pragma unroll
    for (int pp = 0; pp < 2; pp++) {
        int pt = w * 2 + pp;
#pragma unroll
        for (int kt = 0; kt < 4; kt++)
            b_lds[pt][kt][lane] = *reinterpret_cast<const bf16x8*>(We2b + (pt * 16 + col) * D_ + kt * 32 + kg * 8);
    }
    for (int i = t; i < CM_ * 3; i += 256) xr_l[i] = x_r[cm * 3 + i];
    if (t < CM_) as_l[t] = a_s[n * M_ + cm + t];
    if (t < D_) {
        Aq_l[t] = Aq[n * D_ + t];
        w1r_l[t] = w1r[t] * -C_LOG2E;
        bw_l[t] = make_float2(be2[t] * -C_LOG2E, Ws[t] * -C_LN2);
    }
    __syncthreads();   // the only block-wide barrier before the epilogue

    float xq0 = x_q[n * 3 + 0], xq1 = x_q[n * 3 + 1], xq2 = x_q[n * 3 + 2];
    float dxa = 0.f, dya = 0.f, dza = 0.f;

#pragma unroll
    for (int it = 0; it < CM_ / 64; it++) {
        int pm = it * 64 + w * 16 + col;
        float d0 = xq0 - xr_l[pm * 3], d1 = xq1 - xr_l[pm * 3 + 1], d2 = xq2 - xr_l[pm * 3 + 2];
        float radial = d0 * d0 + d1 * d1 + d2 * d2;
        float ir = rsqrtf(radial + 1e-8f);
        // build af (h1 fragments) in registers; y = -log2e * h1arg
        bf16x8 af[4];
#pragma unroll
        for (int kt = 0; kt < 4; kt++) {
            int ob = kt * 32 + kg * 8;
            const float4* brp = reinterpret_cast<const float4*>(Br + (cm + pm) * D_ + ob);
            float4 b0 = brp[0], b1 = brp[1];
            const float4 a0 = *(const float4*)(Aq_l + ob), a1 = *(const float4*)(Aq_l + ob + 4);
            const float4 w0 = *(const float4*)(w1r_l + ob), w1 = *(const float4*)(w1r_l + ob + 4);
            float y0 = a0.x + b0.x + radial * w0.x;
            float y1 = a0.y + b0.y + radial * w0.y;
            float y2 = a0.z + b0.z + radial * w0.z;
            float y3 = a0.w + b0.w + radial * w0.w;
            float y4 = a1.x + b1.x + radial * w1.x;
            float y5 = a1.y + b1.y + radial * w1.y;
            float y6 = a1.z + b1.z + radial * w1.z;
            float y7 = a1.w + b1.w + radial * w1.w;
            float s0 = (y0 * -C_LN2) * __builtin_amdgcn_rcpf(1.f + __builtin_amdgcn_exp2f(y0));
            float s1 = (y1 * -C_LN2) * __builtin_amdgcn_rcpf(1.f + __builtin_amdgcn_exp2f(y1));
            float s2 = (y2 * -C_LN2) * __builtin_amdgcn_rcpf(1.f + __builtin_amdgcn_exp2f(y2));
            float s3 = (y3 * -C_LN2) * __builtin_amdgcn_rcpf(1.f + __builtin_amdgcn_exp2f(y3));
            float s4 = (y4 * -C_LN2) * __builtin_amdgcn_rcpf(1.f + __builtin_amdgcn_exp2f(y4));
            float s5 = (y5 * -C_LN2) * __builtin_amdgcn_rcpf(1.f + __builtin_amdgcn_exp2f(y5));
            float s6 = (y6 * -C_LN2) * __builtin_amdgcn_rcpf(1.f + __builtin_amdgcn_exp2f(y6));
            float s7 = (y7 * -C_LN2) * __builtin_amdgcn_rcpf(1.f + __builtin_amdgcn_exp2f(y7));
            u32x4 afp;
            afp[0] = f2bf_pk(s0, s1);
            afp[1] = f2bf_pk(s2, s3);
            afp[2] = f2bf_pk(s4, s5);
            afp[3] = f2bf_pk(s6, s7);
            af[kt] = *reinterpret_cast<bf16x8*>(&afp);
        }
        // p-sweep: acc = c*(We2 . silu_h); layer-2 silu via exp2, Ws fold
        float svt = 0.f;
#pragma unroll 2
        for (int pt = 0; pt < 8; pt++) {
            f32x4 acc = {0.f, 0.f, 0.f, 0.f};
#pragma unroll
            for (int kt = 0; kt < 4; kt++)
                acc = __builtin_amdgcn_mfma_f32_16x16x32_bf16(b_lds[pt][kt][lane], af[kt], acc, 0, 0, 0);
#pragma unroll
            for (int r = 0; r < 4; r++) {
                float2 bw = bw_l[pt * 16 + kg * 4 + r];
                float y = acc[r] + bw.x;     // = -log2e * (z)
                float rc = __builtin_amdgcn_rcpf(1.f + __builtin_amdgcn_exp2f(y));
                svt = fmaf(y * rc, bw.y, svt);   // y*rc*(-ln2*Ws) = silu(z)*Ws
            }
        }
        float sw = svt * as_l[pm];
        dxa += d0 * ir * sw;
        dya += d1 * ir * sw;
        dza += d2 * ir * sw;
    }
    // wave-level reduce, then tiny cross-wave combine
#pragma unroll
    for (int o = 1; o < 64; o <<= 1) {
        dxa += __shfl_xor(dxa, o);
        dya += __shfl_xor(dya, o);
        dza += __shfl_xor(dza, o);
    }
    if (lane == 0) { dxw[w][0] = dxa; dxw[w][1] = dya; dxw[w][2] = dza; }
    __syncthreads();
    if (t == 0) {
        float* o = dxp + (chunk * N_ + n) * 3;
        o[0] = dxw[0][0] + dxw[1][0] + dxw[2][0] + dxw[3][0];
        o[1] = dxw[0][1] + dxw[1][1] + dxw[2][1] + dxw[3][1];
        o[2] = dxw[0][2] + dxw[1][2] + dxw[2][2] + dxw[3][2];
    }
}

// ---- finalize ----
__global__ __launch_bounds__(256) void k_fin(const float* __restrict__ x_q,
                                             const float* __restrict__ dxp,
                                             const float* __restrict__ gate,
                                             float* __restrict__ x_out) {
    int i = blockIdx.x * 256 + threadIdx.x;
    if (i >= N_ * 3) return;
    int n = i / 3;
    float s = 0.f;
#pragma unroll
    for (int ch = 0; ch < CH_; ch++) s += dxp[(ch * N_ + n) * 3 + (i - n * 3)];
    x_out[i] = x_q[i] + s * gate[n];
}

extern "C" void kernel_launch(void* const* d_in, const int* in_sizes, int n_in,
                              void* d_out, int out_size, void* d_ws, size_t ws_size,
                              hipStream_t stream) {
    const float* h_q   = (const float*)d_in[0];
    const float* x_q   = (const float*)d_in[1];
    const float* h_r   = (const float*)d_in[2];
    const float* x_r   = (const float*)d_in[3];
    const float* Wq    = (const float*)d_in[6];
    const float* bqp   = (const float*)d_in[7];
    const float* Wk    = (const float*)d_in[8];
    const float* bkp   = (const float*)d_in[9];
    const float* Wv    = (const float*)d_in[10];
    const float* bvp   = (const float*)d_in[11];
    const float* Wo    = (const float*)d_in[12];
    const float* bop   = (const float*)d_in[13];
    const float* g_nq  = (const float*)d_in[14];
    const float* b_nq  = (const float*)d_in[15];
    const float* g_nr  = (const float*)d_in[16];
    const float* b_nr  = (const float*)d_in[17];
    const float* g_ff  = (const float*)d_in[18];
    const float* b_ff  = (const float*)d_in[19];
    const float* W1    = (const float*)d_in[20];
    const float* b1    = (const float*)d_in[21];
    const float* W2    = (const float*)d_in[22];
    const float* b2    = (const float*)d_in[23];
    const float* k_null= (const float*)d_in[24];
    const float* v_null= (const float*)d_in[25];
    const float* b_null= (const float*)d_in[26];
    const float* We1   = (const float*)d_in[27];
    const float* be1   = (const float*)d_in[28];
    const float* We2   = (const float*)d_in[29];
    const float* be2   = (const float*)d_in[30];
    const float* Ws    = (const float*)d_in[31];

    float* ws     = (float*)d_ws;
    float* qh     = ws;                   // N*D
    float* rh     = qh + N_ * D_;         // M*D
    float* q      = rh + M_ * D_;         // N*D
    unsigned short* kb = (unsigned short*)(q + N_ * D_);  // M*D bf16
    unsigned short* vb = kb + M_ * D_;                    // M*D bf16
    float* a_s    = (float*)(vb + M_ * D_);  // N*M
    float* gate   = a_s + N_ * M_;        // N
    float* msg    = gate + N_;            // N*D
    float* qh_new = msg + N_ * D_;        // N*D
    float* Aq     = qh_new + N_ * D_;     // N*D
    float* Br     = Aq + N_ * D_;         // M*D
    float* We1a   = Br + M_ * D_;         // 257*128 (row 256 = w1r)
    float* dxp    = We1a + 257 * D_;      // CH*N*3
    unsigned short* We2b = (unsigned short*)(dxp + CH_ * N_ * 3);  // D*D bf16
    float* w1r    = We1a + 256 * D_;

    float* h_out = (float*)d_out;         // N*D
    float* x_out = h_out + N_ * D_;       // N*3

    k_ln2<<<N_ + M_, 64, 0, stream>>>(h_q, h_r, g_nq, b_nq, g_nr, b_nr, qh, rh, We2, We2b, We1, We1a);
    k_qkv<<<dim3(96, 3), 128, 0, stream>>>(qh, rh, h_r, Wq, bqp, Wk, bkp, Wv, bvp, q, kb, vb);
    k_attn<<<N_, 512, 0, stream>>>(q, kb, vb, k_null, v_null, b_null, a_s, gate, msg);
    k_mlp<<<192, 256, 0, stream>>>(h_q, msg, Wo, bop, g_ff, b_ff, W1, b1, W2, b2, g_nq, b_nq, h_out, qh_new);
    k_pre<<<192, 256, 0, stream>>>(qh_new, rh, We1a, be1, Aq, Br);
    k_pair<<<dim3(N_, CH_), 256, 0, stream>>>(x_q, x_r, Aq, Br, w1r, be2, Ws, We2b, a_s, dxp);
    k_fin<<<9, 256, 0, stream>>>(x_q, dxp, gate, x_out);
}

// Round 18
// 147.141 us; speedup vs baseline: 1.0515x; 1.0009x over previous
//
#include <hip/hip_runtime.h>
#include <hip/hip_bf16.h>
#include <math.h>

#define N_ 768
#define M_ 768
#define D_ 128
#define H_ 8
#define DH_ 16
#define FF_ 512
#define CH_ 3
#define CM_ 256   // M_/CH_

#define C_LOG2E 1.44269504f
#define C_LN2   0.69314718f

typedef float f32x4 __attribute__((ext_vector_type(4)));
typedef short bf16x8 __attribute__((ext_vector_type(8)));
typedef unsigned short u16x8 __attribute__((ext_vector_type(8)));
typedef unsigned int u32x4 __attribute__((ext_vector_type(4)));

__device__ __forceinline__ float siluf(float x) {
    return x * __builtin_amdgcn_rcpf(1.0f + __expf(-x));
}

__device__ __forceinline__ unsigned short f2bf(float x) {
    unsigned int u = __float_as_uint(x);
    unsigned int r = (u + 0x7fffu + ((u >> 16) & 1u)) >> 16;
    return (unsigned short)r;
}

__device__ __forceinline__ short f2bf_rn(float x) {
    __hip_bfloat16 b = __float2bfloat16(x);
    return (short)*reinterpret_cast<unsigned short*>(&b);
}

__device__ __forceinline__ unsigned int f2bf_pk(float lo, float hi) {
    __hip_bfloat162 h2 = __float22bfloat162_rn(make_float2(lo, hi));
    return *reinterpret_cast<unsigned int*>(&h2);
}

__device__ __forceinline__ float bf2f(unsigned short u) {
    return __uint_as_float(((unsigned int)u) << 16);
}

// ---- LN for qh & rh rows + We2->bf16 cvt (scaled by -log2e) + We1 transpose ----
__global__ __launch_bounds__(64) void k_ln2(const float* __restrict__ h_q,
                                            const float* __restrict__ h_r,
                                            const float* __restrict__ g_nq, const float* __restrict__ b_nq,
                                            const float* __restrict__ g_nr, const float* __restrict__ b_nr,
                                            float* __restrict__ qh, float* __restrict__ rh,
                                            const float* __restrict__ We2, unsigned short* __restrict__ We2b,
                                            const float* __restrict__ We1, float* __restrict__ We1a) {
    int row = blockIdx.x, lane = threadIdx.x;
    const float *src, *g, *b; float* dst;
    if (row < N_) { src = h_q + row * D_; g = g_nq; b = b_nq; dst = qh + row * D_; }
    else { src = h_r + (row - N_) * D_; g = g_nr; b = b_nr; dst = rh + (row - N_) * D_; }
    float x0 = src[lane], x1 = src[lane + 64];
    float s = x0 + x1;
#pragma unroll
    for (int o = 32; o > 0; o >>= 1) s += __shfl_xor(s, o);
    float mu = s * (1.f / 128.f);
    float d0 = x0 - mu, d1 = x1 - mu;
    float v2 = d0 * d0 + d1 * d1;
#pragma unroll
    for (int o = 32; o > 0; o >>= 1) v2 += __shfl_xor(v2, o);
    float inv = rsqrtf(v2 * (1.f / 128.f) + 1e-5f);
    dst[lane] = d0 * inv * g[lane] + b[lane];
    dst[lane + 64] = d1 * inv * g[lane + 64] + b[lane + 64];
    if (row < D_) {
        We2b[row * D_ + lane] = f2bf(We2[row * D_ + lane] * -C_LOG2E);
        We2b[row * D_ + lane + 64] = f2bf(We2[row * D_ + lane + 64] * -C_LOG2E);
    }
    if (row <= 256) {
        We1a[row * D_ + lane] = We1[lane * 257 + row];
        We1a[row * D_ + lane + 64] = We1[(lane + 64) * 257 + row];
    }
}

// ---- q/k/v projections, 8 rows per block; k,v emitted as bf16 ----
__global__ __launch_bounds__(128) void k_qkv(const float* __restrict__ qh,
                                             const float* __restrict__ rh,
                                             const float* __restrict__ h_r,
                                             const float* __restrict__ Wq, const float* __restrict__ bq,
                                             const float* __restrict__ Wk, const float* __restrict__ bk,
                                             const float* __restrict__ Wv, const float* __restrict__ bv,
                                             float* __restrict__ q,
                                             unsigned short* __restrict__ kb,
                                             unsigned short* __restrict__ vb) {
    int r0 = blockIdx.x * 8, which = blockIdx.y, j = threadIdx.x;
    const float* in; const float* W; const float* b;
    if (which == 0) { in = qh; W = Wq; b = bq; }
    else if (which == 1) { in = rh; W = Wk; b = bk; }
    else { in = h_r; W = Wv; b = bv; }
    __shared__ float xs[8][D_];
    for (int i = j; i < 8 * D_; i += 128) xs[i >> 7][i & 127] = in[r0 * D_ + i];
    __syncthreads();
    const float4* Wr = (const float4*)(W + j * D_);
    float acc[8] = {0, 0, 0, 0, 0, 0, 0, 0};
    for (int i = 0; i < 32; i++) {
        float4 w = Wr[i];
#pragma unroll
        for (int r = 0; r < 8; r++) {
            float4 x = ((const float4*)xs[r])[i];
            acc[r] += w.x * x.x + w.y * x.y + w.z * x.z + w.w * x.w;
        }
    }
    float bb = b[j];
    if (which == 0) {
#pragma unroll
        for (int r = 0; r < 8; r++) q[(r0 + r) * D_ + j] = acc[r] + bb;
    } else {
        unsigned short* outb = (which == 1) ? kb : vb;
#pragma unroll
        for (int r = 0; r < 8; r++) outb[(r0 + r) * D_ + j] = (unsigned short)f2bf_rn(acc[r] + bb);
    }
}

// ---- attention: one wave per (n, head); bf16 K/V; one barrier ----
__global__ __launch_bounds__(512) void k_attn(const float* __restrict__ q,
                                              const unsigned short* __restrict__ kb,
                                              const unsigned short* __restrict__ vb,
                                              const float* __restrict__ k_null,
                                              const float* __restrict__ v_null,
                                              const float* __restrict__ b_null,
                                              float* __restrict__ a_s,
                                              float* __restrict__ gate,
                                              float* __restrict__ msg) {
    int n = blockIdx.x, t = threadIdx.x;
    int h = t >> 6, lane = t & 63;
    __shared__ float ew[H_][M_];
    __shared__ float gate_p[H_];
    const float inv = 0.25f;

    float qr[DH_];
    const float* qp = q + n * D_ + h * DH_;
#pragma unroll
    for (int d = 0; d < DH_; d++) qr[d] = qp[d];

    float ll[12];
    float lmax = -3.4e38f;
#pragma unroll
    for (int i = 0; i < 12; i++) {
        int m = lane + 64 * i;
        const unsigned short* kp = kb + m * D_ + h * DH_;
        u16x8 k0 = *(const u16x8*)kp;
        u16x8 k1 = *(const u16x8*)(kp + 8);
        float acc = 0.f;
#pragma unroll
        for (int d = 0; d < 8; d++) acc += qr[d] * bf2f(k0[d]);
#pragma unroll
        for (int d = 0; d < 8; d++) acc += qr[d + 8] * bf2f(k1[d]);
        acc *= inv;
        ll[i] = acc;
        lmax = fmaxf(lmax, acc);
    }
#pragma unroll
    for (int o = 32; o > 0; o >>= 1) lmax = fmaxf(lmax, __shfl_xor(lmax, o));
    float es = 0.f;
#pragma unroll
    for (int i = 0; i < 12; i++) es += __expf(ll[i] - lmax);
#pragma unroll
    for (int o = 32; o > 0; o >>= 1) es += __shfl_xor(es, o);

    float lnull;
    {
        const float* kp = k_null + h * DH_;
        float acc = 0.f;
#pragma unroll
        for (int d = 0; d < DH_; d++) acc += qr[d] * kp[d];
        lnull = acc * inv + b_null[h];
    }
    float lse_real = lmax + __logf(es + 1e-9f);
    float m2 = fmaxf(lse_real, lnull);
    float lse_all = m2 + __logf(__expf(lse_real - m2) + __expf(lnull - m2));
    float a_null = __expf(lnull - lse_all);
    if (lane == 0) gate_p[h] = fminf(1.f, __expf(lse_real - lse_all));

#pragma unroll
    for (int i = 0; i < 12; i++) ew[h][lane + 64 * i] = __expf(ll[i] - lse_all);

    int d = lane & 15, sub = lane >> 4;
    float p = 0.f;
    const f32x4* ewv = (const f32x4*)&ew[h][0];
#pragma unroll 4
    for (int i = 0; i < 48; i++) {
        int m0 = i * 16 + sub * 4;
        f32x4 a4 = ewv[i * 4 + sub];
        const unsigned short* vp = vb + m0 * D_ + h * DH_ + d;
        p += a4[0] * bf2f(vp[0]);
        p += a4[1] * bf2f(vp[D_]);
        p += a4[2] * bf2f(vp[2 * D_]);
        p += a4[3] * bf2f(vp[3 * D_]);
    }
    p += __shfl_xor(p, 16);
    p += __shfl_xor(p, 32);
    if (lane < 16) msg[n * D_ + h * DH_ + lane] = p + a_null * v_null[h * DH_ + lane];

    __syncthreads();
    for (int m = t; m < M_; m += 512) {
        float s = 0.f;
#pragma unroll
        for (int hh = 0; hh < H_; hh++) s += ew[hh][m];
        a_s[n * M_ + m] = s * 0.125f;
    }
    if (t == 0) {
        float s = 0.f;
#pragma unroll
        for (int hh = 0; hh < H_; hh++) s += gate_p[hh];
        gate[n] = s * 0.125f;
    }
}

// ---- fused outproj + LN + ffn1 + ffn2 + LN, 4 rows per block (192 blocks) ----
__global__ __launch_bounds__(256) void k_mlp(const float* __restrict__ h_q,
                                             const float* __restrict__ msg,
                                             const float* __restrict__ Wo, const float* __restrict__ bop,
                                             const float* __restrict__ g_ff, const float* __restrict__ b_ff,
                                             const float* __restrict__ W1, const float* __restrict__ b1,
                                             const float* __restrict__ W2, const float* __restrict__ b2,
                                             const float* __restrict__ g_nq, const float* __restrict__ b_nq,
                                             float* __restrict__ h_out, float* __restrict__ qh_new) {
    int r0 = blockIdx.x * 4;
    int t = threadIdx.x;
    __shared__ float xs[4][D_];
    __shared__ float hm[4][D_];
    __shared__ float tl[4][D_];
    __shared__ float ffh[4][FF_];
    for (int i = t; i < 4 * D_; i += 256) xs[i >> 7][i & 127] = msg[r0 * D_ + i];
    __syncthreads();
    {
        int g = t >> 7, j = t & 127;
        float acc[2] = {0, 0};
        const float4* Wr = (const float4*)(Wo + j * D_);
        for (int i = 0; i < 32; i++) {
            float4 w = Wr[i];
#pragma unroll
            for (int r = 0; r < 2; r++) {
                float4 x = ((const float4*)xs[2 * g + r])[i];
                acc[r] += w.x * x.x + w.y * x.y + w.z * x.z + w.w * x.w;
            }
        }
        float bb = bop[j];
#pragma unroll
        for (int r = 0; r < 2; r++)
            hm[2 * g + r][j] = h_q[(r0 + 2 * g + r) * D_ + j] + acc[r] + bb;
    }
    __syncthreads();
    {
        int r = t >> 6, l = t & 63;
        float v0 = hm[r][l], v1 = hm[r][l + 64];
        float s = v0 + v1;
#pragma unroll
        for (int o = 32; o > 0; o >>= 1) s += __shfl_xor(s, o);
        float mu = s * (1.f / 128.f);
        float d0 = v0 - mu, d1 = v1 - mu;
        float vv = d0 * d0 + d1 * d1;
#pragma unroll
        for (int o = 32; o > 0; o >>= 1) vv += __shfl_xor(vv, o);
        float inv = rsqrtf(vv * (1.f / 128.f) + 1e-5f);
        tl[r][l] = d0 * inv * g_ff[l] + b_ff[l];
        tl[r][l + 64] = d1 * inv * g_ff[l + 64] + b_ff[l + 64];
    }
    __syncthreads();
    {
        int j0 = t, j1 = t + 256;
        float a0[4] = {0}, a1[4] = {0};
        const float4* Wa = (const float4*)(W1 + j0 * D_);
        const float4* Wb = (const float4*)(W1 + j1 * D_);
        for (int i = 0; i < 32; i++) {
            float4 wa = Wa[i], wb = Wb[i];
#pragma unroll
            for (int r = 0; r < 4; r++) {
                float4 x = ((const float4*)tl[r])[i];
                a0[r] += wa.x * x.x + wa.y * x.y + wa.z * x.z + wa.w * x.w;
                a1[r] += wb.x * x.x + wb.y * x.y + wb.z * x.z + wb.w * x.w;
            }
        }
        float bb0 = b1[j0], bb1 = b1[j1];
#pragma unroll
        for (int r = 0; r < 4; r++) {
            ffh[r][j0] = siluf(a0[r] + bb0);
            ffh[r][j1] = siluf(a1[r] + bb1);
        }
    }
    __syncthreads();
    {
        int g = t >> 7, j = t & 127;
        float acc[2] = {0, 0};
        const float4* Wr = (const float4*)(W2 + j * FF_);
        for (int i = 0; i < 128; i++) {
            float4 w = Wr[i];
#pragma unroll
            for (int r = 0; r < 2; r++) {
                float4 x = ((const float4*)ffh[2 * g + r])[i];
                acc[r] += w.x * x.x + w.y * x.y + w.z * x.z + w.w * x.w;
            }
        }
        float bb = b2[j];
#pragma unroll
        for (int r = 0; r < 2; r++) {
            float vv = hm[2 * g + r][j] + acc[r] + bb;
            h_out[(r0 + 2 * g + r) * D_ + j] = vv;
            hm[2 * g + r][j] = vv;
        }
    }
    __syncthreads();
    {
        int r = t >> 6, l = t & 63;
        float v0 = hm[r][l], v1 = hm[r][l + 64];
        float s = v0 + v1;
#pragma unroll
        for (int o = 32; o > 0; o >>= 1) s += __shfl_xor(s, o);
        float mu = s * (1.f / 128.f);
        float d0 = v0 - mu, d1 = v1 - mu;
        float vv = d0 * d0 + d1 * d1;
#pragma unroll
        for (int o = 32; o > 0; o >>= 1) vv += __shfl_xor(vv, o);
        float inv = rsqrtf(vv * (1.f / 128.f) + 1e-5f);
        int rr = (r0 + r) * D_;
        qh_new[rr + l] = d0 * inv * g_nq[l] + b_nq[l];
        qh_new[rr + l + 64] = d1 * inv * g_nq[l + 64] + b_nq[l + 64];
    }
}

// ---- edge-MLP layer-1 precompute (outputs pre-scaled by -log2e) ----
__global__ __launch_bounds__(256) void k_pre(const float* __restrict__ qh_new,
                                             const float* __restrict__ rh,
                                             const float* __restrict__ We1a,
                                             const float* __restrict__ be1,
                                             float* __restrict__ Aq,
                                             float* __restrict__ Br) {
    int bb = blockIdx.x;               // 0..191
    int half = bb >= 96;
    int r0 = (bb - half * 96) * 8;
    int off = half * 128;
    int t = threadIdx.x;
    int r = t >> 5, jg = t & 31;       // row 0..7, j-group of 4
    __shared__ float xs[8][D_];
    const float* in = (half ? rh : qh_new) + r0 * D_;
    for (int i = t; i < 8 * D_; i += 256) xs[i >> 7][i & 127] = in[i];
    __syncthreads();
    float acc[4] = {0, 0, 0, 0};
    const float* xr = xs[r];
    for (int i = 0; i < 128; i++) {
        float x = xr[i];
        const float4 w0 = *(const float4*)(We1a + (off + i) * D_ + jg * 4);
        acc[0] += w0.x * x; acc[1] += w0.y * x; acc[2] += w0.z * x; acc[3] += w0.w * x;
    }
    if (half) {
        const float4 e0 = *(const float4*)(be1 + jg * 4);
        acc[0] += e0.x; acc[1] += e0.y; acc[2] += e0.z; acc[3] += e0.w;
    }
    float* out = (half ? Br : Aq) + (r0 + r) * D_ + jg * 4;
    *(float4*)(out) = make_float4(acc[0] * -C_LOG2E, acc[1] * -C_LOG2E,
                                  acc[2] * -C_LOG2E, acc[3] * -C_LOG2E);
}

// ---- pair kernel: r17 + pt-unroll 4 (4 MFMA chains in flight) ----
__global__ __launch_bounds__(256, 3) void k_pair(const float* __restrict__ x_q,
                                                 const float* __restrict__ x_r,
                                                 const float* __restrict__ Aq,
                                                 const float* __restrict__ Br,
                                                 const float* __restrict__ w1r,
                                                 const float* __restrict__ be2,
                                                 const float* __restrict__ Ws,
                                                 const unsigned short* __restrict__ We2b,
                                                 const float* __restrict__ a_s,
                                                 float* __restrict__ dxp) {
    int n = blockIdx.x;
    int chunk = blockIdx.y;
    int cm = chunk * CM_;
    int t = threadIdx.x;
    int w = t >> 6;
    int lane = t & 63;
    int col = lane & 15;
    int kg = lane >> 4;

    __shared__ bf16x8 b_lds[8][4][64];   // 32 KB: We2 fragments (c-scaled)
    __shared__ float xr_l[CM_ * 3];      // 3 KB
    __shared__ float as_l[CM_];          // 1 KB
    __shared__ float Aq_l[D_];           // c-scaled (from k_pre)
    __shared__ float w1r_l[D_];          // c-scaled here
    __shared__ float2 bw_l[D_];          // (c*be2, -ln2*Ws)
    __shared__ float dxw[4][3];

#pragma unroll
    for (int pp = 0; pp < 2; pp++) {
        int pt = w * 2 + pp;
#pragma unroll
        for (int kt = 0; kt < 4; kt++)
            b_lds[pt][kt][lane] = *reinterpret_cast<const bf16x8*>(We2b + (pt * 16 + col) * D_ + kt * 32 + kg * 8);
    }
    for (int i = t; i < CM_ * 3; i += 256) xr_l[i] = x_r[cm * 3 + i];
    if (t < CM_) as_l[t] = a_s[n * M_ + cm + t];
    if (t < D_) {
        Aq_l[t] = Aq[n * D_ + t];
        w1r_l[t] = w1r[t] * -C_LOG2E;
        bw_l[t] = make_float2(be2[t] * -C_LOG2E, Ws[t] * -C_LN2);
    }
    __syncthreads();   // the only block-wide barrier before the epilogue

    float xq0 = x_q[n * 3 + 0], xq1 = x_q[n * 3 + 1], xq2 = x_q[n * 3 + 2];
    float dxa = 0.f, dya = 0.f, dza = 0.f;

#pragma unroll
    for (int it = 0; it < CM_ / 64; it++) {
        int pm = it * 64 + w * 16 + col;
        float d0 = xq0 - xr_l[pm * 3], d1 = xq1 - xr_l[pm * 3 + 1], d2 = xq2 - xr_l[pm * 3 + 2];
        float radial = d0 * d0 + d1 * d1 + d2 * d2;
        float ir = rsqrtf(radial + 1e-8f);
        // build af (h1 fragments) in registers; y = -log2e * h1arg
        bf16x8 af[4];
#pragma unroll
        for (int kt = 0; kt < 4; kt++) {
            int ob = kt * 32 + kg * 8;
            const float4* brp = reinterpret_cast<const float4*>(Br + (cm + pm) * D_ + ob);
            float4 b0 = brp[0], b1 = brp[1];
            const float4 a0 = *(const float4*)(Aq_l + ob), a1 = *(const float4*)(Aq_l + ob + 4);
            const float4 w0 = *(const float4*)(w1r_l + ob), w1 = *(const float4*)(w1r_l + ob + 4);
            float y0 = a0.x + b0.x + radial * w0.x;
            float y1 = a0.y + b0.y + radial * w0.y;
            float y2 = a0.z + b0.z + radial * w0.z;
            float y3 = a0.w + b0.w + radial * w0.w;
            float y4 = a1.x + b1.x + radial * w1.x;
            float y5 = a1.y + b1.y + radial * w1.y;
            float y6 = a1.z + b1.z + radial * w1.z;
            float y7 = a1.w + b1.w + radial * w1.w;
            float s0 = (y0 * -C_LN2) * __builtin_amdgcn_rcpf(1.f + __builtin_amdgcn_exp2f(y0));
            float s1 = (y1 * -C_LN2) * __builtin_amdgcn_rcpf(1.f + __builtin_amdgcn_exp2f(y1));
            float s2 = (y2 * -C_LN2) * __builtin_amdgcn_rcpf(1.f + __builtin_amdgcn_exp2f(y2));
            float s3 = (y3 * -C_LN2) * __builtin_amdgcn_rcpf(1.f + __builtin_amdgcn_exp2f(y3));
            float s4 = (y4 * -C_LN2) * __builtin_amdgcn_rcpf(1.f + __builtin_amdgcn_exp2f(y4));
            float s5 = (y5 * -C_LN2) * __builtin_amdgcn_rcpf(1.f + __builtin_amdgcn_exp2f(y5));
            float s6 = (y6 * -C_LN2) * __builtin_amdgcn_rcpf(1.f + __builtin_amdgcn_exp2f(y6));
            float s7 = (y7 * -C_LN2) * __builtin_amdgcn_rcpf(1.f + __builtin_amdgcn_exp2f(y7));
            u32x4 afp;
            afp[0] = f2bf_pk(s0, s1);
            afp[1] = f2bf_pk(s2, s3);
            afp[2] = f2bf_pk(s4, s5);
            afp[3] = f2bf_pk(s6, s7);
            af[kt] = *reinterpret_cast<bf16x8*>(&afp);
        }
        // p-sweep: 4 independent MFMA chains in flight (latency hiding)
        float svt = 0.f;
#pragma unroll 4
        for (int pt = 0; pt < 8; pt++) {
            f32x4 acc = {0.f, 0.f, 0.f, 0.f};
#pragma unroll
            for (int kt = 0; kt < 4; kt++)
                acc = __builtin_amdgcn_mfma_f32_16x16x32_bf16(b_lds[pt][kt][lane], af[kt], acc, 0, 0, 0);
#pragma unroll
            for (int r = 0; r < 4; r++) {
                float2 bw = bw_l[pt * 16 + kg * 4 + r];
                float y = acc[r] + bw.x;     // = -log2e * (z)
                float rc = __builtin_amdgcn_rcpf(1.f + __builtin_amdgcn_exp2f(y));
                svt = fmaf(y * rc, bw.y, svt);   // y*rc*(-ln2*Ws) = silu(z)*Ws
            }
        }
        float sw = svt * as_l[pm];
        dxa += d0 * ir * sw;
        dya += d1 * ir * sw;
        dza += d2 * ir * sw;
    }
    // wave-level reduce, then tiny cross-wave combine
#pragma unroll
    for (int o = 1; o < 64; o <<= 1) {
        dxa += __shfl_xor(dxa, o);
        dya += __shfl_xor(dya, o);
        dza += __shfl_xor(dza, o);
    }
    if (lane == 0) { dxw[w][0] = dxa; dxw[w][1] = dya; dxw[w][2] = dza; }
    __syncthreads();
    if (t == 0) {
        float* o = dxp + (chunk * N_ + n) * 3;
        o[0] = dxw[0][0] + dxw[1][0] + dxw[2][0] + dxw[3][0];
        o[1] = dxw[0][1] + dxw[1][1] + dxw[2][1] + dxw[3][1];
        o[2] = dxw[0][2] + dxw[1][2] + dxw[2][2] + dxw[3][2];
    }
}

// ---- finalize ----
__global__ __launch_bounds__(256) void k_fin(const float* __restrict__ x_q,
                                             const float* __restrict__ dxp,
                                             const float* __restrict__ gate,
                                             float* __restrict__ x_out) {
    int i = blockIdx.x * 256 + threadIdx.x;
    if (i >= N_ * 3) return;
    int n = i / 3;
    float s = 0.f;
#pragma unroll
    for (int ch = 0; ch < CH_; ch++) s += dxp[(ch * N_ + n) * 3 + (i - n * 3)];
    x_out[i] = x_q[i] + s * gate[n];
}

extern "C" void kernel_launch(void* const* d_in, const int* in_sizes, int n_in,
                              void* d_out, int out_size, void* d_ws, size_t ws_size,
                              hipStream_t stream) {
    const float* h_q   = (const float*)d_in[0];
    const float* x_q   = (const float*)d_in[1];
    const float* h_r   = (const float*)d_in[2];
    const float* x_r   = (const float*)d_in[3];
    const float* Wq    = (const float*)d_in[6];
    const float* bqp   = (const float*)d_in[7];
    const float* Wk    = (const float*)d_in[8];
    const float* bkp   = (const float*)d_in[9];
    const float* Wv    = (const float*)d_in[10];
    const float* bvp   = (const float*)d_in[11];
    const float* Wo    = (const float*)d_in[12];
    const float* bop   = (const float*)d_in[13];
    const float* g_nq  = (const float*)d_in[14];
    const float* b_nq  = (const float*)d_in[15];
    const float* g_nr  = (const float*)d_in[16];
    const float* b_nr  = (const float*)d_in[17];
    const float* g_ff  = (const float*)d_in[18];
    const float* b_ff  = (const float*)d_in[19];
    const float* W1    = (const float*)d_in[20];
    const float* b1    = (const float*)d_in[21];
    const float* W2    = (const float*)d_in[22];
    const float* b2    = (const float*)d_in[23];
    const float* k_null= (const float*)d_in[24];
    const float* v_null= (const float*)d_in[25];
    const float* b_null= (const float*)d_in[26];
    const float* We1   = (const float*)d_in[27];
    const float* be1   = (const float*)d_in[28];
    const float* We2   = (const float*)d_in[29];
    const float* be2   = (const float*)d_in[30];
    const float* Ws    = (const float*)d_in[31];

    float* ws     = (float*)d_ws;
    float* qh     = ws;                   // N*D
    float* rh     = qh + N_ * D_;         // M*D
    float* q      = rh + M_ * D_;         // N*D
    unsigned short* kb = (unsigned short*)(q + N_ * D_);  // M*D bf16
    unsigned short* vb = kb + M_ * D_;                    // M*D bf16
    float* a_s    = (float*)(vb + M_ * D_);  // N*M
    float* gate   = a_s + N_ * M_;        // N
    float* msg    = gate + N_;            // N*D
    float* qh_new = msg + N_ * D_;        // N*D
    float* Aq     = qh_new + N_ * D_;     // N*D
    float* Br     = Aq + N_ * D_;         // M*D
    float* We1a   = Br + M_ * D_;         // 257*128 (row 256 = w1r)
    float* dxp    = We1a + 257 * D_;      // CH*N*3
    unsigned short* We2b = (unsigned short*)(dxp + CH_ * N_ * 3);  // D*D bf16
    float* w1r    = We1a + 256 * D_;

    float* h_out = (float*)d_out;         // N*D
    float* x_out = h_out + N_ * D_;       // N*3

    k_ln2<<<N_ + M_, 64, 0, stream>>>(h_q, h_r, g_nq, b_nq, g_nr, b_nr, qh, rh, We2, We2b, We1, We1a);
    k_qkv<<<dim3(96, 3), 128, 0, stream>>>(qh, rh, h_r, Wq, bqp, Wk, bkp, Wv, bvp, q, kb, vb);
    k_attn<<<N_, 512, 0, stream>>>(q, kb, vb, k_null, v_null, b_null, a_s, gate, msg);
    k_mlp<<<192, 256, 0, stream>>>(h_q, msg, Wo, bop, g_ff, b_ff, W1, b1, W2, b2, g_nq, b_nq, h_out, qh_new);
    k_pre<<<192, 256, 0, stream>>>(qh_new, rh, We1a, be1, Aq, Br);
    k_pair<<<dim3(N_, CH_), 256, 0, stream>>>(x_q, x_r, Aq, Br, w1r, be2, Ws, We2b, a_s, dxp);
    k_fin<<<9, 256, 0, stream>>>(x_q, dxp, gate, x_out);
}